// Round 4
// baseline (1309.901 us; speedup 1.0000x reference)
//
#include <hip/hip_runtime.h>

#define T_SEQ 769
#define N_SENT 768
#define E_IN 256
#define HID 128
#define G4 512
#define F_DIM 128

typedef _Float16 h2t __attribute__((ext_vector_type(2)));

#if __has_builtin(__builtin_amdgcn_fdot2)
#define FDOT2(a, b, c) __builtin_amdgcn_fdot2((a), (b), (c), false)
#else
#define FDOT2(a, b, c) fmaf((float)(a).x, (float)(b).x, fmaf((float)(a).y, (float)(b).y, (c)))
#endif

__device__ __forceinline__ float sigm(float x) {
    return 1.0f / (1.0f + __expf(-x));
}
__device__ __forceinline__ float tanh_f(float x) {
    return 1.0f - 2.0f / (1.0f + __expf(2.0f * x));
}
__device__ __forceinline__ h2t u2h(unsigned u) { return __builtin_bit_cast(h2t, u); }

// x = concat(sentence (768x256), root (1x256))
__global__ void build_x(const float* __restrict__ sent, const float* __restrict__ root,
                        float* __restrict__ x) {
    int row = blockIdx.x;
    int c = threadIdx.x;
    x[row * E_IN + c] = (row < N_SENT) ? sent[row * E_IN + c] : root[c];
}

// C[m,n] = sum_k A[ar(m),k] * B[n,k] + b0[n] + b1[n]
__global__ __launch_bounds__(256) void gemm_nt(
    const float* __restrict__ A, int lda, int M, int revA,
    const float* __restrict__ B, int ldb,
    const float* __restrict__ b0, const float* __restrict__ b1,
    float* __restrict__ C, int ldc, int K)
{
    __shared__ __align__(16) float As[16][68];
    __shared__ __align__(16) float Bs[16][68];
    int tid = threadIdx.x;
    int tx = tid & 15, ty = tid >> 4;
    int m0 = blockIdx.x * 64, n0 = blockIdx.y * 64;
    float acc[4][4] = {};
    int lrow = tid >> 2;
    int lk = (tid & 3) << 2;

    for (int k0 = 0; k0 < K; k0 += 16) {
        int m = m0 + lrow;
        float4 av = make_float4(0.f, 0.f, 0.f, 0.f);
        if (m < M) {
            int ar = revA ? (M - 1 - m) : m;
            av = *(const float4*)(A + (size_t)ar * lda + k0 + lk);
        }
        As[lk + 0][lrow] = av.x; As[lk + 1][lrow] = av.y;
        As[lk + 2][lrow] = av.z; As[lk + 3][lrow] = av.w;
        float4 bv = *(const float4*)(B + (size_t)(n0 + lrow) * ldb + k0 + lk);
        Bs[lk + 0][lrow] = bv.x; Bs[lk + 1][lrow] = bv.y;
        Bs[lk + 2][lrow] = bv.z; Bs[lk + 3][lrow] = bv.w;
        __syncthreads();
        #pragma unroll
        for (int k = 0; k < 16; ++k) {
            float4 a4 = *(const float4*)&As[k][ty * 4];
            float4 b4 = *(const float4*)&Bs[k][tx * 4];
            float aa[4] = {a4.x, a4.y, a4.z, a4.w};
            float bb[4] = {b4.x, b4.y, b4.z, b4.w};
            #pragma unroll
            for (int i = 0; i < 4; ++i)
                #pragma unroll
                for (int j = 0; j < 4; ++j)
                    acc[i][j] = fmaf(aa[i], bb[j], acc[i][j]);
        }
        __syncthreads();
    }
    float bias[4];
    #pragma unroll
    for (int j = 0; j < 4; ++j) {
        int n = n0 + tx * 4 + j;
        bias[j] = (b0 ? b0[n] : 0.f) + (b1 ? b1[n] : 0.f);
    }
    #pragma unroll
    for (int i = 0; i < 4; ++i) {
        int m = m0 + ty * 4 + i;
        if (m < M) {
            #pragma unroll
            for (int j = 0; j < 4; ++j)
                C[(size_t)m * ldc + n0 + tx * 4 + j] = acc[i][j] + bias[j];
        }
    }
}

// One BiLSTM layer. grid = 2 (dir 0 fwd, dir 1 bwd), block = 256 (4 waves).
// Thread (u, half): all 4 gate partial-dots of unit u over K-half (64 of 128).
// LDS traffic per step: 32 broadcast b128 h-reads + 4 b128 partial writes +
// 4 b128 partial reads + 1 b16 h write (per CU, wave-instr counts).
__global__ __launch_bounds__(256, 1) void lstm_layer(
    const float* __restrict__ pre,
    const float* __restrict__ Whh,
    float* __restrict__ L)
{
    const int d = blockIdx.x;
    const int t = threadIdx.x;
    const int u = t & 127;
    const int half = t >> 7;

    __shared__ __align__(16) unsigned short hb[2][HID];   // h as f16, double-buffered
    __shared__ __align__(16) float part[HID][2][4];       // [unit][half][gate]

    // weights: gate g, unit u, K in [half*64, half*64+64) as 32 half2 -> 128 VGPRs
    h2t w[4][32];
    #pragma unroll
    for (int g = 0; g < 4; ++g) {
        const float* wr = Whh + ((size_t)d * G4 + g * HID + u) * HID + half * 64;
        #pragma unroll
        for (int k = 0; k < 32; ++k) {
            float2 v = *(const float2*)(wr + 2 * k);
            h2t p2 = {(_Float16)v.x, (_Float16)v.y};
            w[g][k] = p2;
        }
    }

    if (t < HID) hb[0][t] = 0;  // f16 +0.0
    float c = 0.f;
    const float* pd = pre + (size_t)d * T_SEQ * G4;
    float pv[4] = {0.f, 0.f, 0.f, 0.f};
    if (t < HID) {
        #pragma unroll
        for (int g = 0; g < 4; ++g) pv[g] = pd[g * HID + u];
    }
    __syncthreads();

    for (int step = 0; step < T_SEQ; ++step) {
        // prefetch next-step pre (finisher threads), in flight across the dot phase
        float pn[4] = {0.f, 0.f, 0.f, 0.f};
        if (t < HID && step + 1 < T_SEQ) {
            #pragma unroll
            for (int g = 0; g < 4; ++g)
                pn[g] = pd[(size_t)(step + 1) * G4 + g * HID + u];
        }

        const uint4* hp = (const uint4*)&hb[step & 1][half * 64];
        float a0 = 0.f, a1 = 0.f, a2 = 0.f, a3 = 0.f;
        #pragma unroll
        for (int k = 0; k < 8; ++k) {
            uint4 hv = hp[k];  // wave-uniform broadcast (this wave's K-half)
            a0 = FDOT2(w[0][k * 4 + 0], u2h(hv.x), a0);
            a1 = FDOT2(w[1][k * 4 + 0], u2h(hv.x), a1);
            a2 = FDOT2(w[2][k * 4 + 0], u2h(hv.x), a2);
            a3 = FDOT2(w[3][k * 4 + 0], u2h(hv.x), a3);
            a0 = FDOT2(w[0][k * 4 + 1], u2h(hv.y), a0);
            a1 = FDOT2(w[1][k * 4 + 1], u2h(hv.y), a1);
            a2 = FDOT2(w[2][k * 4 + 1], u2h(hv.y), a2);
            a3 = FDOT2(w[3][k * 4 + 1], u2h(hv.y), a3);
            a0 = FDOT2(w[0][k * 4 + 2], u2h(hv.z), a0);
            a1 = FDOT2(w[1][k * 4 + 2], u2h(hv.z), a1);
            a2 = FDOT2(w[2][k * 4 + 2], u2h(hv.z), a2);
            a3 = FDOT2(w[3][k * 4 + 2], u2h(hv.z), a3);
            a0 = FDOT2(w[0][k * 4 + 3], u2h(hv.w), a0);
            a1 = FDOT2(w[1][k * 4 + 3], u2h(hv.w), a1);
            a2 = FDOT2(w[2][k * 4 + 3], u2h(hv.w), a2);
            a3 = FDOT2(w[3][k * 4 + 3], u2h(hv.w), a3);
        }
        *(float4*)&part[u][half][0] = make_float4(a0, a1, a2, a3);
        __syncthreads();

        if (t < HID) {
            float4 pa = *(const float4*)&part[u][0][0];
            float4 pb = *(const float4*)&part[u][1][0];
            float gi = sigm(pa.x + pb.x + pv[0]);
            float gf = sigm(pa.y + pb.y + pv[1]);
            float gg = tanh_f(pa.z + pb.z + pv[2]);
            float go = sigm(pa.w + pb.w + pv[3]);
            c = fmaf(gf, c, gi * gg);
            float h = go * tanh_f(c);
            int trow = d ? (N_SENT - step) : step;
            L[(size_t)trow * 256 + d * HID + u] = h;
            _Float16 hf = (_Float16)h;
            hb[(step + 1) & 1][u] = __builtin_bit_cast(unsigned short, hf);
            pv[0] = pn[0]; pv[1] = pn[1]; pv[2] = pn[2]; pv[3] = pn[3];
        }
        __syncthreads();
    }
}

// scores[i][j] = (i==j) ? -1e30 : b2 + sum_k w2[k]*tanh(Ap[i][k] + Bm[j][k])
__global__ __launch_bounds__(256) void scores_k(
    const float* __restrict__ Ap,   // [769][128]
    const float* __restrict__ Bm,   // [768][128]
    const float* __restrict__ w2,
    const float* __restrict__ b2,
    float* __restrict__ out)        // [769][768]
{
    __shared__ __align__(16) float Asl[32][132];
    __shared__ __align__(16) float Bsl[32][132];
    __shared__ __align__(16) float w2s[F_DIM];
    int tid = threadIdx.x;
    int i0 = blockIdx.x * 32, j0 = blockIdx.y * 32;

    for (int e = tid; e < 1024; e += 256) {
        int r = e >> 5;
        int q = (e & 31) << 2;
        float4 av = (i0 + r < T_SEQ)
                        ? *(const float4*)(Ap + (size_t)(i0 + r) * F_DIM + q)
                        : make_float4(0.f, 0.f, 0.f, 0.f);
        *(float4*)&Asl[r][q] = av;
        float4 bv = *(const float4*)(Bm + (size_t)(j0 + r) * F_DIM + q);
        *(float4*)&Bsl[r][q] = bv;
    }
    if (tid < 32) {
        *(float4*)&w2s[tid * 4] = *(const float4*)(w2 + tid * 4);
    }
    __syncthreads();

    int tx = tid & 15, ty = tid >> 4;
    float s[2][2] = {};
    #pragma unroll 8
    for (int k4 = 0; k4 < F_DIM; k4 += 4) {
        float4 a0 = *(const float4*)&Asl[ty * 2][k4];
        float4 a1 = *(const float4*)&Asl[ty * 2 + 1][k4];
        float4 b0 = *(const float4*)&Bsl[tx * 2][k4];
        float4 b1v = *(const float4*)&Bsl[tx * 2 + 1][k4];
        float4 wv = *(const float4*)&w2s[k4];
        float aa[2][4] = {{a0.x, a0.y, a0.z, a0.w}, {a1.x, a1.y, a1.z, a1.w}};
        float bb[2][4] = {{b0.x, b0.y, b0.z, b0.w}, {b1v.x, b1v.y, b1v.z, b1v.w}};
        float ww[4] = {wv.x, wv.y, wv.z, wv.w};
        #pragma unroll
        for (int kk = 0; kk < 4; ++kk)
            #pragma unroll
            for (int ii = 0; ii < 2; ++ii)
                #pragma unroll
                for (int jj = 0; jj < 2; ++jj)
                    s[ii][jj] = fmaf(ww[kk], tanh_f(aa[ii][kk] + bb[jj][kk]), s[ii][jj]);
    }

    float bb2 = b2[0];
    #pragma unroll
    for (int ii = 0; ii < 2; ++ii) {
        int i = i0 + ty * 2 + ii;
        if (i < T_SEQ) {
            #pragma unroll
            for (int jj = 0; jj < 2; ++jj) {
                int j = j0 + tx * 2 + jj;
                out[(size_t)i * N_SENT + j] =
                    (i == j) ? -1.0e30f : (s[ii][jj] + bb2);
            }
        }
    }
}

extern "C" void kernel_launch(void* const* d_in, const int* in_sizes, int n_in,
                              void* d_out, int out_size, void* d_ws, size_t ws_size,
                              hipStream_t stream) {
    const float* sent = (const float*)d_in[0];
    const float* root = (const float*)d_in[2];
    const float* Wih  = (const float*)d_in[3];  // (2,2,512,256)
    const float* Whh  = (const float*)d_in[4];  // (2,2,512,128)
    const float* bih  = (const float*)d_in[5];  // (2,2,512)
    const float* bhh  = (const float*)d_in[6];  // (2,2,512)
    const float* W1   = (const float*)d_in[7];  // (128,512)
    const float* b1   = (const float*)d_in[8];  // (128)
    const float* w2   = (const float*)d_in[9];  // (128)
    const float* b2   = (const float*)d_in[10]; // (1)
    float* out = (float*)d_out;
    float* ws = (float*)d_ws;

    float* x   = ws;                       // 769*256
    float* pre = x + T_SEQ * E_IN;         // 2*769*512
    float* L0  = pre + 2 * T_SEQ * G4;     // 769*256
    float* L1  = L0 + T_SEQ * 256;         // 769*256
    float* Ap  = L1 + T_SEQ * 256;         // 769*128
    float* Bm  = Ap + T_SEQ * F_DIM;       // 768*128

    build_x<<<T_SEQ, E_IN, 0, stream>>>(sent, root, x);

    dim3 b256(256);
    dim3 gpre(13, 8);
    gemm_nt<<<gpre, b256, 0, stream>>>(x, E_IN, T_SEQ, 0,
                                       Wih, E_IN, bih, bhh, pre, G4, E_IN);
    gemm_nt<<<gpre, b256, 0, stream>>>(x, E_IN, T_SEQ, 1,
                                       Wih + (size_t)G4 * E_IN, E_IN,
                                       bih + G4, bhh + G4,
                                       pre + (size_t)T_SEQ * G4, G4, E_IN);
    lstm_layer<<<2, 256, 0, stream>>>(pre, Whh, L0);

    gemm_nt<<<gpre, b256, 0, stream>>>(L0, 256, T_SEQ, 0,
                                       Wih + (size_t)2 * G4 * E_IN, 256,
                                       bih + 2 * G4, bhh + 2 * G4, pre, G4, 256);
    gemm_nt<<<gpre, b256, 0, stream>>>(L0, 256, T_SEQ, 1,
                                       Wih + (size_t)3 * G4 * E_IN, 256,
                                       bih + 3 * G4, bhh + 3 * G4,
                                       pre + (size_t)T_SEQ * G4, G4, 256);
    lstm_layer<<<2, 256, 0, stream>>>(pre, Whh + (size_t)2 * G4 * HID, L1);

    gemm_nt<<<dim3(13, 2), b256, 0, stream>>>(L1, 256, T_SEQ, 0,
                                              W1, 512, b1, nullptr, Ap, F_DIM, 256);
    gemm_nt<<<dim3(12, 2), b256, 0, stream>>>(L1, 256, N_SENT, 0,
                                              W1 + 256, 512, nullptr, nullptr, Bm, F_DIM, 256);

    scores_k<<<dim3(25, 24), b256, 0, stream>>>(Ap, Bm, w2, b2, out);
}

// Round 6
// 1092.627 us; speedup vs baseline: 1.1989x; 1.1989x over previous
//
#include <hip/hip_runtime.h>

#define T_SEQ 769
#define N_SENT 768
#define E_IN 256
#define HID 128
#define G4 512
#define F_DIM 128

typedef _Float16 h2t __attribute__((ext_vector_type(2)));

#if __has_builtin(__builtin_amdgcn_fdot2)
#define FDOT2(a, b, c) __builtin_amdgcn_fdot2((a), (b), (c), false)
#else
#define FDOT2(a, b, c) fmaf((float)(a).x, (float)(b).x, fmaf((float)(a).y, (float)(b).y, (c)))
#endif

#if __has_builtin(__builtin_amdgcn_rcpf)
#define RCPF(x) __builtin_amdgcn_rcpf(x)
#else
#define RCPF(x) (1.0f / (x))
#endif

// v_exp_f32: D = 2^S0  (avoid __exp2f which collides with glibc math.h macros)
#if __has_builtin(__builtin_amdgcn_exp2f)
#define EXP2F(x) __builtin_amdgcn_exp2f(x)
#else
#define EXP2F(x) __builtin_exp2f(x)
#endif

// LDS-only barrier: waits lgkmcnt(0) then s_barrier. Does NOT drain vmcnt,
// so global prefetch loads stay in flight across the barrier (the compiler's
// __syncthreads always emits s_waitcnt vmcnt(0) first, serializing the
// prefetch into the step's critical path).
#define LDS_BARRIER() asm volatile("s_waitcnt lgkmcnt(0)\n\ts_barrier" ::: "memory")

__device__ __forceinline__ float sigm(float x) {
    return 1.0f / (1.0f + __expf(-x));
}
__device__ __forceinline__ float tanh_f(float x) {
    return 1.0f - 2.0f / (1.0f + __expf(2.0f * x));
}
__device__ __forceinline__ h2t u2h(unsigned u) { return __builtin_bit_cast(h2t, u); }

// x = concat(sentence (768x256), root (1x256))
__global__ void build_x(const float* __restrict__ sent, const float* __restrict__ root,
                        float* __restrict__ x) {
    int row = blockIdx.x;
    int c = threadIdx.x;
    x[row * E_IN + c] = (row < N_SENT) ? sent[row * E_IN + c] : root[c];
}

// C[m,n] = sum_k A[ar(m),k] * B[n,k] + b0[n] + b1[n]
__global__ __launch_bounds__(256) void gemm_nt(
    const float* __restrict__ A, int lda, int M, int revA,
    const float* __restrict__ B, int ldb,
    const float* __restrict__ b0, const float* __restrict__ b1,
    float* __restrict__ C, int ldc, int K)
{
    __shared__ __align__(16) float As[16][68];
    __shared__ __align__(16) float Bs[16][68];
    int tid = threadIdx.x;
    int tx = tid & 15, ty = tid >> 4;
    int m0 = blockIdx.x * 64, n0 = blockIdx.y * 64;
    float acc[4][4] = {};
    int lrow = tid >> 2;
    int lk = (tid & 3) << 2;

    for (int k0 = 0; k0 < K; k0 += 16) {
        int m = m0 + lrow;
        float4 av = make_float4(0.f, 0.f, 0.f, 0.f);
        if (m < M) {
            int ar = revA ? (M - 1 - m) : m;
            av = *(const float4*)(A + (size_t)ar * lda + k0 + lk);
        }
        As[lk + 0][lrow] = av.x; As[lk + 1][lrow] = av.y;
        As[lk + 2][lrow] = av.z; As[lk + 3][lrow] = av.w;
        float4 bv = *(const float4*)(B + (size_t)(n0 + lrow) * ldb + k0 + lk);
        Bs[lk + 0][lrow] = bv.x; Bs[lk + 1][lrow] = bv.y;
        Bs[lk + 2][lrow] = bv.z; Bs[lk + 3][lrow] = bv.w;
        __syncthreads();
        #pragma unroll
        for (int k = 0; k < 16; ++k) {
            float4 a4 = *(const float4*)&As[k][ty * 4];
            float4 b4 = *(const float4*)&Bs[k][tx * 4];
            float aa[4] = {a4.x, a4.y, a4.z, a4.w};
            float bb[4] = {b4.x, b4.y, b4.z, b4.w};
            #pragma unroll
            for (int i = 0; i < 4; ++i)
                #pragma unroll
                for (int j = 0; j < 4; ++j)
                    acc[i][j] = fmaf(aa[i], bb[j], acc[i][j]);
        }
        __syncthreads();
    }
    float bias[4];
    #pragma unroll
    for (int j = 0; j < 4; ++j) {
        int n = n0 + tx * 4 + j;
        bias[j] = (b0 ? b0[n] : 0.f) + (b1 ? b1[n] : 0.f);
    }
    #pragma unroll
    for (int i = 0; i < 4; ++i) {
        int m = m0 + ty * 4 + i;
        if (m < M) {
            #pragma unroll
            for (int j = 0; j < 4; ++j)
                C[(size_t)m * ldc + n0 + tx * 4 + j] = acc[i][j] + bias[j];
        }
    }
}

// One BiLSTM layer. grid = 2 (dir 0 fwd, dir 1 bwd), block = 512 (8 waves).
// Lane mapping: wave w, lane l -> unit u = w*16 + (l>>2), gate g = l&3.
// Each thread computes one full gate row (64 half2 weights in VGPRs).
// All 4 gates of a unit live in one lane-quad -> gather via 3 shfl_xor, no
// second barrier. One LDS-only barrier per step; global pre prefetch
// (distance 2) stays in flight across it.
__global__ __launch_bounds__(512, 2) void lstm_layer(
    const float* __restrict__ pre,
    const float* __restrict__ Whh,
    float* __restrict__ L)
{
    const int d = blockIdx.x;
    const int t = threadIdx.x;
    const int wv_id = t >> 6;
    const int l = t & 63;
    const int u = wv_id * 16 + (l >> 2);
    const int g = l & 3;
    const int row = g * HID + u;

    __shared__ __align__(16) unsigned short hb[2][HID];  // h as f16, double-buffered

    // activation constants: gates i,f,o -> sigmoid; gate 2 -> tanh
    // sigm(x) = rcp(1 + 2^(-1.442695 x)); tanh(x) = 2*rcp(1 + 2^(-2.885390 x)) - 1
    const float Aa = (g == 2) ? 2.0f : 1.0f;
    const float Bb = (g == 2) ? -2.8853900817779268f : -1.4426950408889634f;
    const float Cc = (g == 2) ? -1.0f : 0.0f;

    // register-resident weight row, packed f16 (64 half2 = 64 VGPRs)
    h2t w[HID / 2];
    const float* wr = Whh + ((size_t)d * G4 + row) * HID;
    #pragma unroll
    for (int k = 0; k < HID / 2; ++k) {
        float2 v = *(const float2*)(wr + 2 * k);
        h2t p2v = {(_Float16)v.x, (_Float16)v.y};
        w[k] = p2v;
    }

    if (t < HID) { hb[0][t] = 0; hb[1][t] = 0; }
    float c = 0.f;
    const float* pd = pre + (size_t)d * T_SEQ * G4;
    float p  = pd[row];            // step 0
    float p1 = pd[G4 + row];       // step 1
    __syncthreads();

    for (int s = 0; s < T_SEQ; ++s) {
        // prefetch distance 2: in flight across the barrier (vmcnt not drained)
        float p2 = (s + 2 < T_SEQ) ? pd[(size_t)(s + 2) * G4 + row] : 0.f;

        const uint4* hp = (const uint4*)&hb[s & 1][0];
        float acc = 0.f;
        #pragma unroll
        for (int k = 0; k < 16; ++k) {
            uint4 hv = hp[k];  // wave-uniform broadcast read
            acc = FDOT2(w[4 * k + 0], u2h(hv.x), acc);
            acc = FDOT2(w[4 * k + 1], u2h(hv.y), acc);
            acc = FDOT2(w[4 * k + 2], u2h(hv.z), acc);
            acc = FDOT2(w[4 * k + 3], u2h(hv.w), acc);
        }
        float xg = acc + p;
        // own-gate activation (uniform, no divergence)
        float r = fmaf(Aa, RCPF(1.0f + EXP2F(Bb * xg)), Cc);
        // gather quad: lane base (g=0) ends with r=i, r1=f, r2=g~, r3=o
        float r1 = __shfl_xor(r, 1);
        float r2 = __shfl_xor(r, 2);
        float r3 = __shfl_xor(r1, 2);
        if (g == 0) {
            c = fmaf(r1, c, r * r2);
            float th = fmaf(2.0f, RCPF(1.0f + EXP2F(-2.8853900817779268f * c)), -1.0f);
            float h = r3 * th;
            int trow = d ? (N_SENT - s) : s;
            L[(size_t)trow * 256 + d * HID + u] = h;
            _Float16 hf = (_Float16)h;
            hb[(s + 1) & 1][u] = __builtin_bit_cast(unsigned short, hf);
        }
        p = p1; p1 = p2;
        LDS_BARRIER();
    }
}

// scores[i][j] = (i==j) ? -1e30 : b2 + sum_k w2[k]*tanh(Ap[i][k] + Bm[j][k])
__global__ __launch_bounds__(256) void scores_k(
    const float* __restrict__ Ap,   // [769][128]
    const float* __restrict__ Bm,   // [768][128]
    const float* __restrict__ w2,
    const float* __restrict__ b2,
    float* __restrict__ out)        // [769][768]
{
    __shared__ __align__(16) float Asl[32][132];
    __shared__ __align__(16) float Bsl[32][132];
    __shared__ __align__(16) float w2s[F_DIM];
    int tid = threadIdx.x;
    int i0 = blockIdx.x * 32, j0 = blockIdx.y * 32;

    for (int e = tid; e < 1024; e += 256) {
        int r = e >> 5;
        int q = (e & 31) << 2;
        float4 av = (i0 + r < T_SEQ)
                        ? *(const float4*)(Ap + (size_t)(i0 + r) * F_DIM + q)
                        : make_float4(0.f, 0.f, 0.f, 0.f);
        *(float4*)&Asl[r][q] = av;
        float4 bv = *(const float4*)(Bm + (size_t)(j0 + r) * F_DIM + q);
        *(float4*)&Bsl[r][q] = bv;
    }
    if (tid < 32) {
        *(float4*)&w2s[tid * 4] = *(const float4*)(w2 + tid * 4);
    }
    __syncthreads();

    int tx = tid & 15, ty = tid >> 4;
    float s[2][2] = {};
    #pragma unroll 8
    for (int k4 = 0; k4 < F_DIM; k4 += 4) {
        float4 a0 = *(const float4*)&Asl[ty * 2][k4];
        float4 a1 = *(const float4*)&Asl[ty * 2 + 1][k4];
        float4 b0 = *(const float4*)&Bsl[tx * 2][k4];
        float4 b1v = *(const float4*)&Bsl[tx * 2 + 1][k4];
        float4 wv = *(const float4*)&w2s[k4];
        float aa[2][4] = {{a0.x, a0.y, a0.z, a0.w}, {a1.x, a1.y, a1.z, a1.w}};
        float bb[2][4] = {{b0.x, b0.y, b0.z, b0.w}, {b1v.x, b1v.y, b1v.z, b1v.w}};
        float ww[4] = {wv.x, wv.y, wv.z, wv.w};
        #pragma unroll
        for (int kk = 0; kk < 4; ++kk)
            #pragma unroll
            for (int ii = 0; ii < 2; ++ii)
                #pragma unroll
                for (int jj = 0; jj < 2; ++jj)
                    s[ii][jj] = fmaf(ww[kk], tanh_f(aa[ii][kk] + bb[jj][kk]), s[ii][jj]);
    }

    float bb2 = b2[0];
    #pragma unroll
    for (int ii = 0; ii < 2; ++ii) {
        int i = i0 + ty * 2 + ii;
        if (i < T_SEQ) {
            #pragma unroll
            for (int jj = 0; jj < 2; ++jj) {
                int j = j0 + tx * 2 + jj;
                out[(size_t)i * N_SENT + j] =
                    (i == j) ? -1.0e30f : (s[ii][jj] + bb2);
            }
        }
    }
}

extern "C" void kernel_launch(void* const* d_in, const int* in_sizes, int n_in,
                              void* d_out, int out_size, void* d_ws, size_t ws_size,
                              hipStream_t stream) {
    const float* sent = (const float*)d_in[0];
    const float* root = (const float*)d_in[2];
    const float* Wih  = (const float*)d_in[3];  // (2,2,512,256)
    const float* Whh  = (const float*)d_in[4];  // (2,2,512,128)
    const float* bih  = (const float*)d_in[5];  // (2,2,512)
    const float* bhh  = (const float*)d_in[6];  // (2,2,512)
    const float* W1   = (const float*)d_in[7];  // (128,512)
    const float* b1   = (const float*)d_in[8];  // (128)
    const float* w2   = (const float*)d_in[9];  // (128)
    const float* b2   = (const float*)d_in[10]; // (1)
    float* out = (float*)d_out;
    float* ws = (float*)d_ws;

    float* x   = ws;                       // 769*256
    float* pre = x + T_SEQ * E_IN;         // 2*769*512
    float* L0  = pre + 2 * T_SEQ * G4;     // 769*256
    float* L1  = L0 + T_SEQ * 256;         // 769*256
    float* Ap  = L1 + T_SEQ * 256;         // 769*128
    float* Bm  = Ap + T_SEQ * F_DIM;       // 768*128

    build_x<<<T_SEQ, E_IN, 0, stream>>>(sent, root, x);

    dim3 b256(256);
    dim3 gpre(13, 8);
    gemm_nt<<<gpre, b256, 0, stream>>>(x, E_IN, T_SEQ, 0,
                                       Wih, E_IN, bih, bhh, pre, G4, E_IN);
    gemm_nt<<<gpre, b256, 0, stream>>>(x, E_IN, T_SEQ, 1,
                                       Wih + (size_t)G4 * E_IN, E_IN,
                                       bih + G4, bhh + G4,
                                       pre + (size_t)T_SEQ * G4, G4, E_IN);
    lstm_layer<<<2, 512, 0, stream>>>(pre, Whh, L0);

    gemm_nt<<<gpre, b256, 0, stream>>>(L0, 256, T_SEQ, 0,
                                       Wih + (size_t)2 * G4 * E_IN, 256,
                                       bih + 2 * G4, bhh + 2 * G4, pre, G4, 256);
    gemm_nt<<<gpre, b256, 0, stream>>>(L0, 256, T_SEQ, 1,
                                       Wih + (size_t)3 * G4 * E_IN, 256,
                                       bih + 3 * G4, bhh + 3 * G4,
                                       pre + (size_t)T_SEQ * G4, G4, 256);
    lstm_layer<<<2, 512, 0, stream>>>(pre, Whh + (size_t)2 * G4 * HID, L1);

    gemm_nt<<<dim3(13, 2), b256, 0, stream>>>(L1, 256, T_SEQ, 0,
                                              W1, 512, b1, nullptr, Ap, F_DIM, 256);
    gemm_nt<<<dim3(12, 2), b256, 0, stream>>>(L1, 256, N_SENT, 0,
                                              W1 + 256, 512, nullptr, nullptr, Bm, F_DIM, 256);

    scores_k<<<dim3(25, 24), b256, 0, stream>>>(Ap, Bm, w2, b2, out);
}